// Round 10
// baseline (223.378 us; speedup 1.0000x reference)
//
#include <hip/hip_runtime.h>
#include <hip/hip_bf16.h>

// B=4, S=1024, D=1024, H=16, DH=64. Softmax over HEADS (per (i,j)), per reference.

using f32x4  = __attribute__((ext_vector_type(4))) float;
using f32x2  = __attribute__((ext_vector_type(2))) float;
using bf16x8 = __attribute__((ext_vector_type(8))) short;
using bf16x4 = __attribute__((ext_vector_type(4))) short;

__device__ inline unsigned short f2b(float f){
    unsigned u = __float_as_uint(f);
    unsigned r = (u + 0x7fffu + ((u >> 16) & 1u)) >> 16;
    return (unsigned short)r;
}
__device__ inline float b2f(unsigned short s){
    return __uint_as_float(((unsigned)s) << 16);
}

#define GLL16(gp, lp) __builtin_amdgcn_global_load_lds( \
    (const __attribute__((address_space(1))) void*)(gp), \
    (__attribute__((address_space(3))) void*)(lp), 16, 0, 0)

#define LGKM0 do { asm volatile("s_waitcnt lgkmcnt(0)" ::: "memory"); \
                   __builtin_amdgcn_sched_barrier(0); } while(0)
#define BAR   do { __builtin_amdgcn_s_barrier(); \
                   __builtin_amdgcn_sched_barrier(0); } while(0)

// ---------------- convert q,k,v f32 -> bf16, contiguous [3][4096][1024] -------
__global__ __launch_bounds__(256) void convert_qkv(
    const float* __restrict__ q, const float* __restrict__ k, const float* __restrict__ v,
    unsigned short* __restrict__ dst)
{
    const long gid = (long)blockIdx.x * 256 + threadIdx.x;
    const int  t   = (int)(gid >> 20);
    const long off = (gid & 1048575) << 2;
    const float* src = (t == 0) ? q : (t == 1) ? k : v;
    const float4 x = *(const float4*)(src + off);
    ushort4 o;
    o.x = f2b(x.x); o.y = f2b(x.y); o.z = f2b(x.z); o.w = f2b(x.w);
    *(ushort4*)(dst + (long)t * 4194304 + off) = o;
}

// ---------------- transpose+convert W f32 [k][n] -> bf16 [n][k] ---------------
__global__ __launch_bounds__(256) void wtrans(
    const float* __restrict__ w0, const float* __restrict__ w1,
    const float* __restrict__ w2, const float* __restrict__ w3,
    unsigned short* __restrict__ out)
{
    const float* W = (blockIdx.z == 0) ? w0 : (blockIdx.z == 1) ? w1 : (blockIdx.z == 2) ? w2 : w3;
    unsigned short* O = out + (long)blockIdx.z * 1048576;
    __shared__ float t[32][33];
    const int n0 = blockIdx.x * 32, k0 = blockIdx.y * 32;
    const int tx = threadIdx.x, ty = threadIdx.y;
    #pragma unroll
    for (int i = 0; i < 4; i++)
        t[ty + 8*i][tx] = W[(long)(k0 + ty + 8*i) * 1024 + n0 + tx];
    __syncthreads();
    #pragma unroll
    for (int i = 0; i < 4; i++)
        O[(long)(n0 + ty + 8*i) * 1024 + k0 + tx] = f2b(t[tx][ty + 8*i]);
}

// ---------------- transpose V bf16 [b*1024+s][d] -> Vt [b][d][s] --------------
__global__ __launch_bounds__(256) void vtrans(
    const unsigned short* __restrict__ V, unsigned short* __restrict__ Vt)
{
    const int b = blockIdx.z;
    __shared__ unsigned short t[32][33];
    const int s0 = blockIdx.x * 32, d0 = blockIdx.y * 32;
    const int tx = threadIdx.x, ty = threadIdx.y;
    #pragma unroll
    for (int i = 0; i < 4; i++)
        t[ty + 8*i][tx] = V[(long)(b*1024 + s0 + ty + 8*i) * 1024 + d0 + tx];
    __syncthreads();
    #pragma unroll
    for (int i = 0; i < 4; i++)
        Vt[(long)b * 1048576 + (long)(d0 + ty + 8*i) * 1024 + s0 + tx] = t[tx][ty + 8*i];
}

// ---------------- GEMM tile body (m97 structure) ------------------------------
template<int OUTF32>
__device__ __forceinline__ void gemm_body(
    const unsigned short* __restrict__ A,
    const unsigned short* __restrict__ BT,
    const float* __restrict__ bias,
    void* __restrict__ Cout, int N, int K,
    unsigned short* As, unsigned short* Bs)
{
    const int tid  = threadIdx.x;
    const int wave = tid >> 6, lane = tid & 63;
    const int l15  = lane & 15, l4 = lane >> 4;
    const int wr   = wave >> 1, wc = wave & 1;
    const long rowBase = (long)blockIdx.x * 128;
    const long colBase = (long)blockIdx.y * 128;

    f32x4 acc[4][4];
    #pragma unroll
    for (int m = 0; m < 4; m++)
        #pragma unroll
        for (int n = 0; n < 4; n++)
            acc[m][n] = (f32x4){0.f, 0.f, 0.f, 0.f};

    const int c0    = wave * 2;
    const int srow0 = c0 * 16 + (lane >> 2);
    const int srow1 = srow0 + 16;
    const int skk   = (lane & 3) * 8;

    for (int k0 = 0; k0 < K; k0 += 32) {
        GLL16(A  + (rowBase + srow0) * K + k0 + skk, As + c0 * 512);
        GLL16(A  + (rowBase + srow1) * K + k0 + skk, As + (c0 + 1) * 512);
        GLL16(BT + (colBase + srow0) * K + k0 + skk, Bs + c0 * 512);
        GLL16(BT + (colBase + srow1) * K + k0 + skk, Bs + (c0 + 1) * 512);
        __syncthreads();
        bf16x8 af[4], bfr[4];
        #pragma unroll
        for (int m = 0; m < 4; m++)
            af[m] = *(const bf16x8*)(As + (wr*64 + m*16 + l15) * 32 + l4 * 8);
        #pragma unroll
        for (int n = 0; n < 4; n++)
            bfr[n] = *(const bf16x8*)(Bs + (wc*64 + n*16 + l15) * 32 + l4 * 8);
        #pragma unroll
        for (int m = 0; m < 4; m++)
            #pragma unroll
            for (int n = 0; n < 4; n++)
                acc[m][n] = __builtin_amdgcn_mfma_f32_16x16x32_bf16(af[m], bfr[n], acc[m][n], 0, 0, 0);
        __syncthreads();
    }

    #pragma unroll
    for (int m = 0; m < 4; m++) {
        const long row = rowBase + wr*64 + m*16 + l4*4;
        #pragma unroll
        for (int n = 0; n < 4; n++) {
            const long col = colBase + wc*64 + n*16 + l15;
            const float bv = bias[col];
            #pragma unroll
            for (int r = 0; r < 4; r++) {
                const float vv = acc[m][n][r] + bv;
                if (OUTF32) ((float*)Cout)[(row + r) * N + col] = vv;
                else        ((unsigned short*)Cout)[(row + r) * N + col] = f2b(vv);
            }
        }
    }
}

__global__ __launch_bounds__(256) void gemm_bias_f32(
    const unsigned short* __restrict__ A,
    const unsigned short* __restrict__ BT,
    const float* __restrict__ bias,
    float* __restrict__ Cout, int N, int K)
{
    __shared__ unsigned short As[128 * 32];
    __shared__ unsigned short Bs[128 * 32];
    gemm_body<1>(A, BT, bias, (void*)Cout, N, K, As, Bs);
}

__global__ __launch_bounds__(256) void gemm3(
    const unsigned short* __restrict__ Abase,
    const unsigned short* __restrict__ WT,
    const float* __restrict__ bq, const float* __restrict__ bk, const float* __restrict__ bv,
    unsigned short* __restrict__ Cbase)
{
    __shared__ unsigned short As[128 * 32];
    __shared__ unsigned short Bs[128 * 32];
    const int z = blockIdx.z;
    const unsigned short* A  = Abase + (long)z * 4194304;
    const unsigned short* BT = WT    + (long)z * 1048576;
    unsigned short*       C  = Cbase + (long)z * 4194304;
    const float* bias = (z == 0) ? bq : (z == 1) ? bk : bv;
    gemm_body<0>(A, BT, bias, (void*)C, 1024, 1024, As, Bs);
}

// ---------------- fused attention ---------------------------------------------
// IBLK=16 i-rows; GROUP=32 j; 16 groups over a 512-j half. Grid 512 = 2
// blocks/CU (the round-9 grid of 256 pinned occupancy at 1 block/CU).
// K/V global->reg; LDS = one S buffer [512 ij][18 f32] (36KB); P (18KB)
// ALIASES S. 4 barriers/group: QK->S |B1| softmax |B2: S reads done| P
// writes |B3: P visible| PV |B4: P reads done|.
__global__ __launch_bounds__(512, 2) void attn_fused(
    const unsigned short* __restrict__ Q,    // [4096][1024]
    const unsigned short* __restrict__ Kg_,  // [4096][1024]
    const unsigned short* __restrict__ Vt,   // [4][1024(d)][1024(s)]
    const int* __restrict__ mask,            // [1024*1024]
    unsigned short* __restrict__ P0,
    unsigned short* __restrict__ P1)
{
    __shared__ __align__(16) unsigned char smem[36864];
    float*         S  = (float*)smem;        // [512 ij][18 f32] (72B rows); ij = i*32+j
    unsigned char* Pb = smem;                // [16 h][16 i][72B], aliases S

    const int tid = threadIdx.x, w = tid >> 6, lane = tid & 63;
    const int l15 = lane & 15, l4 = lane >> 4;
    const int h0  = 2 * w;
    const int sxor = h0 ^ (l4 << 2);

    // bijective XCD swizzle: 512 blocks -> 64 consecutive wg per XCD
    const int bid = blockIdx.x;
    const int wg  = (bid & 7) * 64 + (bid >> 3);
    const int b   = wg >> 7;
    const int jh  = (wg >> 6) & 1;
    const int i0  = (wg & 63) << 4;
    const int jbase = jh << 9;

    const unsigned short* Kb = Kg_ + (long)b * 1048576;
    const unsigned short* Vb = Vt  + (long)b * 1048576;
    unsigned short* Pout = (jh == 0) ? P0 : P1;

    const int i_sm = tid >> 5, j_sm = tid & 31;  // softmax thread -> (i, j in group)
    const int xorv = i_sm & 12;                  // un-permutes the S h-slots
    const int mrow = (i0 + i_sm) * 1024 + jbase;

    // ---- Q fragments (persistent, 16 rows)
    bf16x8 qf[2][2];   // [hh][ks]
    #pragma unroll
    for (int hh = 0; hh < 2; hh++)
        #pragma unroll
        for (int ks = 0; ks < 2; ks++)
            qf[hh][ks] = *(const bf16x8*)(Q + (long)(b*1024 + i0 + l15) * 1024
                                          + (h0 + hh) * 64 + ks * 32 + l4 * 8);

#define LOAD_KF(J0) do { \
    _Pragma("unroll") \
    for (int t_ = 0; t_ < 2; t_++) \
        _Pragma("unroll") \
        for (int hh = 0; hh < 2; hh++) \
            _Pragma("unroll") \
            for (int ks = 0; ks < 2; ks++) \
                kf[t_][hh][ks] = *(const bf16x8*)(Kb + (long)((J0) + t_*16 + l15) * 1024 \
                                                   + (h0 + hh) * 64 + ks * 32 + l4 * 8); \
    } while(0)

#define LOAD_VF(J0) do { \
    _Pragma("unroll") \
    for (int hh = 0; hh < 2; hh++) \
        _Pragma("unroll") \
        for (int n = 0; n < 4; n++) \
            vf[hh][n] = *(const bf16x8*)(Vb + (long)((h0 + hh) * 64 + n * 16 + l15) * 1024 \
                                           + (J0) + l4 * 8); \
    } while(0)

    bf16x8 kf[2][2][2];   // [tile e/o][hh][ks]
    bf16x8 vf[2][4];      // [hh][n]
    LOAD_KF(jbase);
    LOAD_VF(jbase);

    f32x4 acc[2][4];      // [hh][n]
    #pragma unroll
    for (int hh = 0; hh < 2; hh++)
        #pragma unroll
        for (int n = 0; n < 4; n++)
            acc[hh][n] = (f32x4){0.f, 0.f, 0.f, 0.f};

    for (int g = 0; g < 16; ++g) {
        const int j0 = jbase + g * 32;
        const int mk = mask[mrow + g * 32 + j_sm];

        // ---- QK^T for both 16-j subtiles (kf in regs)
        #pragma unroll
        for (int t_ = 0; t_ < 2; t_++) {
            f32x4 sv0 = (f32x4){0.f,0.f,0.f,0.f}, sv1 = (f32x4){0.f,0.f,0.f,0.f};
            sv0 = __builtin_amdgcn_mfma_f32_16x16x32_bf16(qf[0][0], kf[t_][0][0], sv0, 0, 0, 0);
            sv0 = __builtin_amdgcn_mfma_f32_16x16x32_bf16(qf[0][1], kf[t_][0][1], sv0, 0, 0, 0);
            sv1 = __builtin_amdgcn_mfma_f32_16x16x32_bf16(qf[1][0], kf[t_][1][0], sv1, 0, 0, 0);
            sv1 = __builtin_amdgcn_mfma_f32_16x16x32_bf16(qf[1][1], kf[t_][1][1], sv1, 0, 0, 0);
            #pragma unroll
            for (int r = 0; r < 4; r++) {
                const int ij = (l4*4 + r) * 32 + t_ * 16 + l15;
                f32x2 pr; pr[0] = sv0[r]; pr[1] = sv1[r];
                *(f32x2*)(S + ij * 18 + sxor) = pr;
            }
        }
        LGKM0; BAR;                      // B1: S visible

        if (g < 15) LOAD_KF(j0 + 32);    // kf consumed -> refill for g+1

        // ---- head-softmax: one pass, one thread per (i,j) of the 32-j group
        unsigned pe[8];
        {
            const float* sp = S + tid * 18;
            float tv[16];
            #pragma unroll
            for (int q_ = 0; q_ < 8; q_++) {
                const f32x2 t2 = *(const f32x2*)(sp + q_ * 2);
                tv[q_*2] = t2[0]; tv[q_*2+1] = t2[1];
            }
            float Z = 0.f;
            #pragma unroll
            for (int h = 0; h < 16; h++) {
                float x = tv[h] * 0.18033688f;   // 0.125 * log2(e)
                if (mk == 0) x = -__builtin_inff();
                float e; asm("v_exp_f32 %0, %1" : "=v"(e) : "v"(x));
                tv[h] = e; Z += e;
            }
            float inv; asm("v_rcp_f32 %0, %1" : "=v"(inv) : "v"(Z));
            #pragma unroll
            for (int h = 0; h < 8; h++) {
                const unsigned lo = (__float_as_uint(tv[2*h]   * inv) + 0x8000u) >> 16;
                const unsigned hi = (__float_as_uint(tv[2*h+1] * inv) + 0x8000u) >> 16;
                pe[h] = lo | (hi << 16);
            }
        }
        BAR;                             // B2: ALL S reads done -> P may overwrite
        #pragma unroll
        for (int h = 0; h < 16; h++) {
            const unsigned short pv = (unsigned short)((h & 1) ? (pe[h >> 1] >> 16) : pe[h >> 1]);
            *(unsigned short*)(Pb + (h ^ xorv) * 1152 + i_sm * 72 + j_sm * 2) = pv;
        }
        LGKM0; BAR;                      // B3: P visible

        // ---- PV, full K=32 (P rows 72B -> paired b64 reads)
        {
            bf16x8 pa[2];
            #pragma unroll
            for (int hh = 0; hh < 2; hh++) {
                const unsigned char* pr = Pb + (h0 + hh) * 1152 + l15 * 72 + l4 * 16;
                bf16x4 lo = *(const bf16x4*)(pr);
                bf16x4 hi = *(const bf16x4*)(pr + 8);
                pa[hh] = (bf16x8){lo[0],lo[1],lo[2],lo[3], hi[0],hi[1],hi[2],hi[3]};
            }
            #pragma unroll
            for (int hh = 0; hh < 2; hh++)
                #pragma unroll
                for (int n = 0; n < 4; n++)
                    acc[hh][n] = __builtin_amdgcn_mfma_f32_16x16x32_bf16(pa[hh], vf[hh][n], acc[hh][n], 0, 0, 0);
        }
        if (g < 15) {
            LOAD_VF(j0 + 32);            // vf consumed -> refill for g+1
            BAR;                         // B4: P reads done; next QK may write S
        }
    }

    // ---- epilogue: bf16 partial
    #pragma unroll
    for (int hh = 0; hh < 2; hh++)
        #pragma unroll
        for (int n = 0; n < 4; n++)
            #pragma unroll
            for (int r = 0; r < 4; r++) {
                const long row = b * 1024 + i0 + l4 * 4 + r;
                Pout[row * 1024 + (h0 + hh) * 64 + n * 16 + l15] = f2b(acc[hh][n][r]);
            }
#undef LOAD_KF
#undef LOAD_VF
}

// ---------------- reduce: P0 += P1 (bf16, in place) ---------------------------
__global__ __launch_bounds__(256) void addp(
    unsigned short* __restrict__ P0, const unsigned short* __restrict__ P1)
{
    const long i = ((long)blockIdx.x * 256 + threadIdx.x) * 8;
    ushort4 a0 = *(const ushort4*)(P0 + i);
    ushort4 a1 = *(const ushort4*)(P0 + i + 4);
    ushort4 b0 = *(const ushort4*)(P1 + i);
    ushort4 b1 = *(const ushort4*)(P1 + i + 4);
    ushort4 o0, o1;
    o0.x = f2b(b2f(a0.x) + b2f(b0.x)); o0.y = f2b(b2f(a0.y) + b2f(b0.y));
    o0.z = f2b(b2f(a0.z) + b2f(b0.z)); o0.w = f2b(b2f(a0.w) + b2f(b0.w));
    o1.x = f2b(b2f(a1.x) + b2f(b1.x)); o1.y = f2b(b2f(a1.y) + b2f(b1.y));
    o1.z = f2b(b2f(a1.z) + b2f(b1.z)); o1.w = f2b(b2f(a1.w) + b2f(b1.w));
    *(ushort4*)(P0 + i) = o0;
    *(ushort4*)(P0 + i + 4) = o1;
}

extern "C" void kernel_launch(void* const* d_in, const int* in_sizes, int n_in,
                              void* d_out, int out_size, void* d_ws, size_t ws_size,
                              hipStream_t stream)
{
    const float* q    = (const float*)d_in[0];
    const float* k    = (const float*)d_in[1];
    const float* v    = (const float*)d_in[2];
    const int*   mask = (const int*)  d_in[3];
    const float* Wq   = (const float*)d_in[4];
    const float* bq   = (const float*)d_in[5];
    const float* Wk   = (const float*)d_in[6];
    const float* bk   = (const float*)d_in[7];
    const float* Wv   = (const float*)d_in[8];
    const float* bv   = (const float*)d_in[9];
    const float* Wo   = (const float*)d_in[10];
    const float* bo   = (const float*)d_in[11];

    unsigned short* ws = (unsigned short*)d_ws;
    const long MS = 1048576;
    unsigned short* WT  = ws;             // 4 transposed weights      [0,4M)
    unsigned short* Xq  = ws + 4*MS;      // bf16 query  -> later Vt   [4M,8M)
    unsigned short* Xk  = ws + 8*MS;      // bf16 key    -> later P0   [8M,12M)
    unsigned short* Xv  = ws + 12*MS;     // bf16 value                [12M,16M)
    unsigned short* Qm  = ws + 16*MS;     // Q projection              [16M,20M)
    unsigned short* Km  = ws + 20*MS;     // K projection              [20M,24M)
    unsigned short* Vm  = ws + 24*MS;     // V projection -> later P1  [24M,28M)
    unsigned short* Vtm = Xq;
    unsigned short* P0  = Xk;
    unsigned short* P1  = Vm;

    convert_qkv<<<12288, 256, 0, stream>>>(q, k, v, Xq);
    wtrans<<<dim3(32, 32, 4), dim3(32, 8), 0, stream>>>(Wq, Wk, Wv, Wo, WT);
    gemm3<<<dim3(32, 8, 3), 256, 0, stream>>>(Xq, WT, bq, bk, bv, Qm);
    vtrans<<<dim3(32, 32, 4), dim3(32, 8), 0, stream>>>(Vm, Vtm);
    attn_fused<<<512, 512, 0, stream>>>(Qm, Km, Vtm, mask, P0, P1);
    addp<<<2048, 256, 0, stream>>>(P0, P1);
    gemm_bias_f32<<<dim3(32, 8), 256, 0, stream>>>(P0, WT + 3*MS, bo, (float*)d_out, 1024, 1024);
}

// Round 11
// 223.360 us; speedup vs baseline: 1.0001x; 1.0001x over previous
//
#include <hip/hip_runtime.h>
#include <hip/hip_bf16.h>

// B=4, S=1024, D=1024, H=16, DH=64. Softmax over HEADS (per (i,j)), per reference.

using f32x4  = __attribute__((ext_vector_type(4))) float;
using f32x2  = __attribute__((ext_vector_type(2))) float;
using bf16x8 = __attribute__((ext_vector_type(8))) short;
using bf16x4 = __attribute__((ext_vector_type(4))) short;

__device__ inline unsigned short f2b(float f){
    unsigned u = __float_as_uint(f);
    unsigned r = (u + 0x7fffu + ((u >> 16) & 1u)) >> 16;
    return (unsigned short)r;
}
__device__ inline float b2f(unsigned short s){
    return __uint_as_float(((unsigned)s) << 16);
}

#define GLL16(gp, lp) __builtin_amdgcn_global_load_lds( \
    (const __attribute__((address_space(1))) void*)(gp), \
    (__attribute__((address_space(3))) void*)(lp), 16, 0, 0)

#define LGKM0 do { asm volatile("s_waitcnt lgkmcnt(0)" ::: "memory"); \
                   __builtin_amdgcn_sched_barrier(0); } while(0)
#define BAR   do { __builtin_amdgcn_s_barrier(); \
                   __builtin_amdgcn_sched_barrier(0); } while(0)

// ---------------- convert q,k,v f32 -> bf16, contiguous [3][4096][1024] -------
__global__ __launch_bounds__(256) void convert_qkv(
    const float* __restrict__ q, const float* __restrict__ k, const float* __restrict__ v,
    unsigned short* __restrict__ dst)
{
    const long gid = (long)blockIdx.x * 256 + threadIdx.x;
    const int  t   = (int)(gid >> 20);
    const long off = (gid & 1048575) << 2;
    const float* src = (t == 0) ? q : (t == 1) ? k : v;
    const float4 x = *(const float4*)(src + off);
    ushort4 o;
    o.x = f2b(x.x); o.y = f2b(x.y); o.z = f2b(x.z); o.w = f2b(x.w);
    *(ushort4*)(dst + (long)t * 4194304 + off) = o;
}

// ---------------- transpose+convert W f32 [k][n] -> bf16 [n][k] ---------------
__global__ __launch_bounds__(256) void wtrans(
    const float* __restrict__ w0, const float* __restrict__ w1,
    const float* __restrict__ w2, const float* __restrict__ w3,
    unsigned short* __restrict__ out)
{
    const float* W = (blockIdx.z == 0) ? w0 : (blockIdx.z == 1) ? w1 : (blockIdx.z == 2) ? w2 : w3;
    unsigned short* O = out + (long)blockIdx.z * 1048576;
    __shared__ float t[32][33];
    const int n0 = blockIdx.x * 32, k0 = blockIdx.y * 32;
    const int tx = threadIdx.x, ty = threadIdx.y;
    #pragma unroll
    for (int i = 0; i < 4; i++)
        t[ty + 8*i][tx] = W[(long)(k0 + ty + 8*i) * 1024 + n0 + tx];
    __syncthreads();
    #pragma unroll
    for (int i = 0; i < 4; i++)
        O[(long)(n0 + ty + 8*i) * 1024 + k0 + tx] = f2b(t[tx][ty + 8*i]);
}

// ---------------- transpose V bf16 [b*1024+s][d] -> Vt [b][d][s] --------------
__global__ __launch_bounds__(256) void vtrans(
    const unsigned short* __restrict__ V, unsigned short* __restrict__ Vt)
{
    const int b = blockIdx.z;
    __shared__ unsigned short t[32][33];
    const int s0 = blockIdx.x * 32, d0 = blockIdx.y * 32;
    const int tx = threadIdx.x, ty = threadIdx.y;
    #pragma unroll
    for (int i = 0; i < 4; i++)
        t[ty + 8*i][tx] = V[(long)(b*1024 + s0 + ty + 8*i) * 1024 + d0 + tx];
    __syncthreads();
    #pragma unroll
    for (int i = 0; i < 4; i++)
        Vt[(long)b * 1048576 + (long)(d0 + ty + 8*i) * 1024 + s0 + tx] = t[tx][ty + 8*i];
}

// ---------------- GEMM tile body (m97 structure) ------------------------------
template<int OUTF32>
__device__ __forceinline__ void gemm_body(
    const unsigned short* __restrict__ A,
    const unsigned short* __restrict__ BT,
    const float* __restrict__ bias,
    void* __restrict__ Cout, int N, int K,
    unsigned short* As, unsigned short* Bs)
{
    const int tid  = threadIdx.x;
    const int wave = tid >> 6, lane = tid & 63;
    const int l15  = lane & 15, l4 = lane >> 4;
    const int wr   = wave >> 1, wc = wave & 1;
    const long rowBase = (long)blockIdx.x * 128;
    const long colBase = (long)blockIdx.y * 128;

    f32x4 acc[4][4];
    #pragma unroll
    for (int m = 0; m < 4; m++)
        #pragma unroll
        for (int n = 0; n < 4; n++)
            acc[m][n] = (f32x4){0.f, 0.f, 0.f, 0.f};

    const int c0    = wave * 2;
    const int srow0 = c0 * 16 + (lane >> 2);
    const int srow1 = srow0 + 16;
    const int skk   = (lane & 3) * 8;

    for (int k0 = 0; k0 < K; k0 += 32) {
        GLL16(A  + (rowBase + srow0) * K + k0 + skk, As + c0 * 512);
        GLL16(A  + (rowBase + srow1) * K + k0 + skk, As + (c0 + 1) * 512);
        GLL16(BT + (colBase + srow0) * K + k0 + skk, Bs + c0 * 512);
        GLL16(BT + (colBase + srow1) * K + k0 + skk, Bs + (c0 + 1) * 512);
        __syncthreads();
        bf16x8 af[4], bfr[4];
        #pragma unroll
        for (int m = 0; m < 4; m++)
            af[m] = *(const bf16x8*)(As + (wr*64 + m*16 + l15) * 32 + l4 * 8);
        #pragma unroll
        for (int n = 0; n < 4; n++)
            bfr[n] = *(const bf16x8*)(Bs + (wc*64 + n*16 + l15) * 32 + l4 * 8);
        #pragma unroll
        for (int m = 0; m < 4; m++)
            #pragma unroll
            for (int n = 0; n < 4; n++)
                acc[m][n] = __builtin_amdgcn_mfma_f32_16x16x32_bf16(af[m], bfr[n], acc[m][n], 0, 0, 0);
        __syncthreads();
    }

    #pragma unroll
    for (int m = 0; m < 4; m++) {
        const long row = rowBase + wr*64 + m*16 + l4*4;
        #pragma unroll
        for (int n = 0; n < 4; n++) {
            const long col = colBase + wc*64 + n*16 + l15;
            const float bv = bias[col];
            #pragma unroll
            for (int r = 0; r < 4; r++) {
                const float vv = acc[m][n][r] + bv;
                if (OUTF32) ((float*)Cout)[(row + r) * N + col] = vv;
                else        ((unsigned short*)Cout)[(row + r) * N + col] = f2b(vv);
            }
        }
    }
}

__global__ __launch_bounds__(256) void gemm_bias_f32(
    const unsigned short* __restrict__ A,
    const unsigned short* __restrict__ BT,
    const float* __restrict__ bias,
    float* __restrict__ Cout, int N, int K)
{
    __shared__ unsigned short As[128 * 32];
    __shared__ unsigned short Bs[128 * 32];
    gemm_body<1>(A, BT, bias, (void*)Cout, N, K, As, Bs);
}

__global__ __launch_bounds__(256) void gemm3(
    const unsigned short* __restrict__ Abase,
    const unsigned short* __restrict__ WT,
    const float* __restrict__ bq, const float* __restrict__ bk, const float* __restrict__ bv,
    unsigned short* __restrict__ Cbase)
{
    __shared__ unsigned short As[128 * 32];
    __shared__ unsigned short Bs[128 * 32];
    const int z = blockIdx.z;
    const unsigned short* A  = Abase + (long)z * 4194304;
    const unsigned short* BT = WT    + (long)z * 1048576;
    unsigned short*       C  = Cbase + (long)z * 4194304;
    const float* bias = (z == 0) ? bq : (z == 1) ? bk : bv;
    gemm_body<0>(A, BT, bias, (void*)C, 1024, 1024, As, Bs);
}

// ---------------- fused attention ---------------------------------------------
// IBLK=16 i-rows; GROUP=32 j; 16 groups over a 512-j half. Grid 512 = 2
// blocks/CU (the round-9 grid of 256 pinned occupancy at 1 block/CU).
// K/V global->reg; LDS = one S buffer [512 ij][18 f32] (36KB); P (18KB)
// ALIASES S. 4 barriers/group: QK->S |B1| softmax |B2: S reads done| P
// writes |B3: P visible| PV |B4: P reads done|.
__global__ __launch_bounds__(512, 2) void attn_fused(
    const unsigned short* __restrict__ Q,    // [4096][1024]
    const unsigned short* __restrict__ Kg_,  // [4096][1024]
    const unsigned short* __restrict__ Vt,   // [4][1024(d)][1024(s)]
    const int* __restrict__ mask,            // [1024*1024]
    unsigned short* __restrict__ P0,
    unsigned short* __restrict__ P1)
{
    __shared__ __align__(16) unsigned char smem[36864];
    float*         S  = (float*)smem;        // [512 ij][18 f32] (72B rows); ij = i*32+j
    unsigned char* Pb = smem;                // [16 h][16 i][72B], aliases S

    const int tid = threadIdx.x, w = tid >> 6, lane = tid & 63;
    const int l15 = lane & 15, l4 = lane >> 4;
    const int h0  = 2 * w;
    const int sxor = h0 ^ (l4 << 2);

    // bijective XCD swizzle: 512 blocks -> 64 consecutive wg per XCD
    const int bid = blockIdx.x;
    const int wg  = (bid & 7) * 64 + (bid >> 3);
    const int b   = wg >> 7;
    const int jh  = (wg >> 6) & 1;
    const int i0  = (wg & 63) << 4;
    const int jbase = jh << 9;

    const unsigned short* Kb = Kg_ + (long)b * 1048576;
    const unsigned short* Vb = Vt  + (long)b * 1048576;
    unsigned short* Pout = (jh == 0) ? P0 : P1;

    const int i_sm = tid >> 5, j_sm = tid & 31;  // softmax thread -> (i, j in group)
    const int xorv = i_sm & 12;                  // un-permutes the S h-slots
    const int mrow = (i0 + i_sm) * 1024 + jbase;

    // ---- Q fragments (persistent, 16 rows)
    bf16x8 qf[2][2];   // [hh][ks]
    #pragma unroll
    for (int hh = 0; hh < 2; hh++)
        #pragma unroll
        for (int ks = 0; ks < 2; ks++)
            qf[hh][ks] = *(const bf16x8*)(Q + (long)(b*1024 + i0 + l15) * 1024
                                          + (h0 + hh) * 64 + ks * 32 + l4 * 8);

#define LOAD_KF(J0) do { \
    _Pragma("unroll") \
    for (int t_ = 0; t_ < 2; t_++) \
        _Pragma("unroll") \
        for (int hh = 0; hh < 2; hh++) \
            _Pragma("unroll") \
            for (int ks = 0; ks < 2; ks++) \
                kf[t_][hh][ks] = *(const bf16x8*)(Kb + (long)((J0) + t_*16 + l15) * 1024 \
                                                   + (h0 + hh) * 64 + ks * 32 + l4 * 8); \
    } while(0)

#define LOAD_VF(J0) do { \
    _Pragma("unroll") \
    for (int hh = 0; hh < 2; hh++) \
        _Pragma("unroll") \
        for (int n = 0; n < 4; n++) \
            vf[hh][n] = *(const bf16x8*)(Vb + (long)((h0 + hh) * 64 + n * 16 + l15) * 1024 \
                                           + (J0) + l4 * 8); \
    } while(0)

    bf16x8 kf[2][2][2];   // [tile e/o][hh][ks]
    bf16x8 vf[2][4];      // [hh][n]
    LOAD_KF(jbase);
    LOAD_VF(jbase);

    f32x4 acc[2][4];      // [hh][n]
    #pragma unroll
    for (int hh = 0; hh < 2; hh++)
        #pragma unroll
        for (int n = 0; n < 4; n++)
            acc[hh][n] = (f32x4){0.f, 0.f, 0.f, 0.f};

    for (int g = 0; g < 16; ++g) {
        const int j0 = jbase + g * 32;
        const int mk = mask[mrow + g * 32 + j_sm];

        // ---- QK^T for both 16-j subtiles (kf in regs)
        #pragma unroll
        for (int t_ = 0; t_ < 2; t_++) {
            f32x4 sv0 = (f32x4){0.f,0.f,0.f,0.f}, sv1 = (f32x4){0.f,0.f,0.f,0.f};
            sv0 = __builtin_amdgcn_mfma_f32_16x16x32_bf16(qf[0][0], kf[t_][0][0], sv0, 0, 0, 0);
            sv0 = __builtin_amdgcn_mfma_f32_16x16x32_bf16(qf[0][1], kf[t_][0][1], sv0, 0, 0, 0);
            sv1 = __builtin_amdgcn_mfma_f32_16x16x32_bf16(qf[1][0], kf[t_][1][0], sv1, 0, 0, 0);
            sv1 = __builtin_amdgcn_mfma_f32_16x16x32_bf16(qf[1][1], kf[t_][1][1], sv1, 0, 0, 0);
            #pragma unroll
            for (int r = 0; r < 4; r++) {
                const int ij = (l4*4 + r) * 32 + t_ * 16 + l15;
                f32x2 pr; pr[0] = sv0[r]; pr[1] = sv1[r];
                *(f32x2*)(S + ij * 18 + sxor) = pr;
            }
        }
        LGKM0; BAR;                      // B1: S visible

        if (g < 15) LOAD_KF(j0 + 32);    // kf consumed -> refill for g+1

        // ---- head-softmax: one pass, one thread per (i,j) of the 32-j group
        unsigned pe[8];
        {
            const float* sp = S + tid * 18;
            float tv[16];
            #pragma unroll
            for (int q_ = 0; q_ < 8; q_++) {
                const f32x2 t2 = *(const f32x2*)(sp + q_ * 2);
                tv[q_*2] = t2[0]; tv[q_*2+1] = t2[1];
            }
            float Z = 0.f;
            #pragma unroll
            for (int h = 0; h < 16; h++) {
                float x = tv[h] * 0.18033688f;   // 0.125 * log2(e)
                if (mk == 0) x = -__builtin_inff();
                float e; asm("v_exp_f32 %0, %1" : "=v"(e) : "v"(x));
                tv[h] = e; Z += e;
            }
            float inv; asm("v_rcp_f32 %0, %1" : "=v"(inv) : "v"(Z));
            #pragma unroll
            for (int h = 0; h < 8; h++) {
                const unsigned lo = (__float_as_uint(tv[2*h]   * inv) + 0x8000u) >> 16;
                const unsigned hi = (__float_as_uint(tv[2*h+1] * inv) + 0x8000u) >> 16;
                pe[h] = lo | (hi << 16);
            }
        }
        BAR;                             // B2: ALL S reads done -> P may overwrite
        #pragma unroll
        for (int h = 0; h < 16; h++) {
            const unsigned short pv = (unsigned short)((h & 1) ? (pe[h >> 1] >> 16) : pe[h >> 1]);
            *(unsigned short*)(Pb + (h ^ xorv) * 1152 + i_sm * 72 + j_sm * 2) = pv;
        }
        LGKM0; BAR;                      // B3: P visible

        // ---- PV, full K=32 (P rows 72B -> paired b64 reads)
        {
            bf16x8 pa[2];
            #pragma unroll
            for (int hh = 0; hh < 2; hh++) {
                const unsigned char* pr = Pb + (h0 + hh) * 1152 + l15 * 72 + l4 * 16;
                bf16x4 lo = *(const bf16x4*)(pr);
                bf16x4 hi = *(const bf16x4*)(pr + 8);
                pa[hh] = (bf16x8){lo[0],lo[1],lo[2],lo[3], hi[0],hi[1],hi[2],hi[3]};
            }
            #pragma unroll
            for (int hh = 0; hh < 2; hh++)
                #pragma unroll
                for (int n = 0; n < 4; n++)
                    acc[hh][n] = __builtin_amdgcn_mfma_f32_16x16x32_bf16(pa[hh], vf[hh][n], acc[hh][n], 0, 0, 0);
        }
        if (g < 15) {
            LOAD_VF(j0 + 32);            // vf consumed -> refill for g+1
            BAR;                         // B4: P reads done; next QK may write S
        }
    }

    // ---- epilogue: bf16 partial
    #pragma unroll
    for (int hh = 0; hh < 2; hh++)
        #pragma unroll
        for (int n = 0; n < 4; n++)
            #pragma unroll
            for (int r = 0; r < 4; r++) {
                const long row = b * 1024 + i0 + l4 * 4 + r;
                Pout[row * 1024 + (h0 + hh) * 64 + n * 16 + l15] = f2b(acc[hh][n][r]);
            }
#undef LOAD_KF
#undef LOAD_VF
}

// ---------------- reduce: P0 += P1 (bf16, in place) ---------------------------
__global__ __launch_bounds__(256) void addp(
    unsigned short* __restrict__ P0, const unsigned short* __restrict__ P1)
{
    const long i = ((long)blockIdx.x * 256 + threadIdx.x) * 8;
    ushort4 a0 = *(const ushort4*)(P0 + i);
    ushort4 a1 = *(const ushort4*)(P0 + i + 4);
    ushort4 b0 = *(const ushort4*)(P1 + i);
    ushort4 b1 = *(const ushort4*)(P1 + i + 4);
    ushort4 o0, o1;
    o0.x = f2b(b2f(a0.x) + b2f(b0.x)); o0.y = f2b(b2f(a0.y) + b2f(b0.y));
    o0.z = f2b(b2f(a0.z) + b2f(b0.z)); o0.w = f2b(b2f(a0.w) + b2f(b0.w));
    o1.x = f2b(b2f(a1.x) + b2f(b1.x)); o1.y = f2b(b2f(a1.y) + b2f(b1.y));
    o1.z = f2b(b2f(a1.z) + b2f(b1.z)); o1.w = f2b(b2f(a1.w) + b2f(b1.w));
    *(ushort4*)(P0 + i) = o0;
    *(ushort4*)(P0 + i + 4) = o1;
}

extern "C" void kernel_launch(void* const* d_in, const int* in_sizes, int n_in,
                              void* d_out, int out_size, void* d_ws, size_t ws_size,
                              hipStream_t stream)
{
    const float* q    = (const float*)d_in[0];
    const float* k    = (const float*)d_in[1];
    const float* v    = (const float*)d_in[2];
    const int*   mask = (const int*)  d_in[3];
    const float* Wq   = (const float*)d_in[4];
    const float* bq   = (const float*)d_in[5];
    const float* Wk   = (const float*)d_in[6];
    const float* bk   = (const float*)d_in[7];
    const float* Wv   = (const float*)d_in[8];
    const float* bv   = (const float*)d_in[9];
    const float* Wo   = (const float*)d_in[10];
    const float* bo   = (const float*)d_in[11];

    unsigned short* ws = (unsigned short*)d_ws;
    const long MS = 1048576;
    unsigned short* WT  = ws;             // 4 transposed weights      [0,4M)
    unsigned short* Xq  = ws + 4*MS;      // bf16 query  -> later Vt   [4M,8M)
    unsigned short* Xk  = ws + 8*MS;      // bf16 key    -> later P0   [8M,12M)
    unsigned short* Xv  = ws + 12*MS;     // bf16 value                [12M,16M)
    unsigned short* Qm  = ws + 16*MS;     // Q projection              [16M,20M)
    unsigned short* Km  = ws + 20*MS;     // K projection              [20M,24M)
    unsigned short* Vm  = ws + 24*MS;     // V projection -> later P1  [24M,28M)
    unsigned short* Vtm = Xq;
    unsigned short* P0  = Xk;
    unsigned short* P1  = Vm;

    convert_qkv<<<12288, 256, 0, stream>>>(q, k, v, Xq);
    wtrans<<<dim3(32, 32, 4), dim3(32, 8), 0, stream>>>(Wq, Wk, Wv, Wo, WT);
    gemm3<<<dim3(32, 8, 3), 256, 0, stream>>>(Xq, WT, bq, bk, bv, Qm);
    vtrans<<<dim3(32, 32, 4), dim3(32, 8), 0, stream>>>(Vm, Vtm);
    attn_fused<<<512, 512, 0, stream>>>(Qm, Km, Vtm, mask, P0, P1);
    addp<<<2048, 256, 0, stream>>>(P0, P1);
    gemm_bias_f32<<<dim3(32, 8), 256, 0, stream>>>(P0, WT + 3*MS, bo, (float*)d_out, 1024, 1024);
}

// Round 12
// 188.453 us; speedup vs baseline: 1.1853x; 1.1852x over previous
//
#include <hip/hip_runtime.h>
#include <hip/hip_bf16.h>

// B=4, S=1024, D=1024, H=16, DH=64. Softmax over HEADS (per (i,j)), per reference.

using f32x4  = __attribute__((ext_vector_type(4))) float;
using f32x2  = __attribute__((ext_vector_type(2))) float;
using bf16x8 = __attribute__((ext_vector_type(8))) short;
using bf16x4 = __attribute__((ext_vector_type(4))) short;

__device__ inline unsigned short f2b(float f){
    unsigned u = __float_as_uint(f);
    unsigned r = (u + 0x7fffu + ((u >> 16) & 1u)) >> 16;
    return (unsigned short)r;
}
__device__ inline float b2f(unsigned short s){
    return __uint_as_float(((unsigned)s) << 16);
}

#define GLL16(gp, lp) __builtin_amdgcn_global_load_lds( \
    (const __attribute__((address_space(1))) void*)(gp), \
    (__attribute__((address_space(3))) void*)(lp), 16, 0, 0)

// ---------------- convert q,k,v f32 -> bf16, contiguous [3][4096][1024] -------
__global__ __launch_bounds__(256) void convert_qkv(
    const float* __restrict__ q, const float* __restrict__ k, const float* __restrict__ v,
    unsigned short* __restrict__ dst)
{
    const long gid = (long)blockIdx.x * 256 + threadIdx.x;
    const int  t   = (int)(gid >> 20);
    const long off = (gid & 1048575) << 2;
    const float* src = (t == 0) ? q : (t == 1) ? k : v;
    const float4 x = *(const float4*)(src + off);
    ushort4 o;
    o.x = f2b(x.x); o.y = f2b(x.y); o.z = f2b(x.z); o.w = f2b(x.w);
    *(ushort4*)(dst + (long)t * 4194304 + off) = o;
}

// ---------------- transpose+convert W f32 [k][n] -> bf16 [n][k] ---------------
__global__ __launch_bounds__(256) void wtrans(
    const float* __restrict__ w0, const float* __restrict__ w1,
    const float* __restrict__ w2, const float* __restrict__ w3,
    unsigned short* __restrict__ out)
{
    const float* W = (blockIdx.z == 0) ? w0 : (blockIdx.z == 1) ? w1 : (blockIdx.z == 2) ? w2 : w3;
    unsigned short* O = out + (long)blockIdx.z * 1048576;
    __shared__ float t[32][33];
    const int n0 = blockIdx.x * 32, k0 = blockIdx.y * 32;
    const int tx = threadIdx.x, ty = threadIdx.y;
    #pragma unroll
    for (int i = 0; i < 4; i++)
        t[ty + 8*i][tx] = W[(long)(k0 + ty + 8*i) * 1024 + n0 + tx];
    __syncthreads();
    #pragma unroll
    for (int i = 0; i < 4; i++)
        O[(long)(n0 + ty + 8*i) * 1024 + k0 + tx] = f2b(t[tx][ty + 8*i]);
}

// ---------------- transpose V bf16 [b*1024+s][d] -> Vt [b][d][s] --------------
__global__ __launch_bounds__(256) void vtrans(
    const unsigned short* __restrict__ V, unsigned short* __restrict__ Vt)
{
    const int b = blockIdx.z;
    __shared__ unsigned short t[32][33];
    const int s0 = blockIdx.x * 32, d0 = blockIdx.y * 32;
    const int tx = threadIdx.x, ty = threadIdx.y;
    #pragma unroll
    for (int i = 0; i < 4; i++)
        t[ty + 8*i][tx] = V[(long)(b*1024 + s0 + ty + 8*i) * 1024 + d0 + tx];
    __syncthreads();
    #pragma unroll
    for (int i = 0; i < 4; i++)
        Vt[(long)b * 1048576 + (long)(d0 + ty + 8*i) * 1024 + s0 + tx] = t[tx][ty + 8*i];
}

// ---------------- GEMM tile body (m97 structure) ------------------------------
template<int OUTF32>
__device__ __forceinline__ void gemm_body(
    const unsigned short* __restrict__ A,
    const unsigned short* __restrict__ BT,
    const float* __restrict__ bias,
    void* __restrict__ Cout, int N, int K,
    unsigned short* As, unsigned short* Bs)
{
    const int tid  = threadIdx.x;
    const int wave = tid >> 6, lane = tid & 63;
    const int l15  = lane & 15, l4 = lane >> 4;
    const int wr   = wave >> 1, wc = wave & 1;
    const long rowBase = (long)blockIdx.x * 128;
    const long colBase = (long)blockIdx.y * 128;

    f32x4 acc[4][4];
    #pragma unroll
    for (int m = 0; m < 4; m++)
        #pragma unroll
        for (int n = 0; n < 4; n++)
            acc[m][n] = (f32x4){0.f, 0.f, 0.f, 0.f};

    const int c0    = wave * 2;
    const int srow0 = c0 * 16 + (lane >> 2);
    const int srow1 = srow0 + 16;
    const int skk   = (lane & 3) * 8;

    for (int k0 = 0; k0 < K; k0 += 32) {
        GLL16(A  + (rowBase + srow0) * K + k0 + skk, As + c0 * 512);
        GLL16(A  + (rowBase + srow1) * K + k0 + skk, As + (c0 + 1) * 512);
        GLL16(BT + (colBase + srow0) * K + k0 + skk, Bs + c0 * 512);
        GLL16(BT + (colBase + srow1) * K + k0 + skk, Bs + (c0 + 1) * 512);
        __syncthreads();
        bf16x8 af[4], bfr[4];
        #pragma unroll
        for (int m = 0; m < 4; m++)
            af[m] = *(const bf16x8*)(As + (wr*64 + m*16 + l15) * 32 + l4 * 8);
        #pragma unroll
        for (int n = 0; n < 4; n++)
            bfr[n] = *(const bf16x8*)(Bs + (wc*64 + n*16 + l15) * 32 + l4 * 8);
        #pragma unroll
        for (int m = 0; m < 4; m++)
            #pragma unroll
            for (int n = 0; n < 4; n++)
                acc[m][n] = __builtin_amdgcn_mfma_f32_16x16x32_bf16(af[m], bfr[n], acc[m][n], 0, 0, 0);
        __syncthreads();
    }

    #pragma unroll
    for (int m = 0; m < 4; m++) {
        const long row = rowBase + wr*64 + m*16 + l4*4;
        #pragma unroll
        for (int n = 0; n < 4; n++) {
            const long col = colBase + wc*64 + n*16 + l15;
            const float bv = bias[col];
            #pragma unroll
            for (int r = 0; r < 4; r++) {
                const float vv = acc[m][n][r] + bv;
                if (OUTF32) ((float*)Cout)[(row + r) * N + col] = vv;
                else        ((unsigned short*)Cout)[(row + r) * N + col] = f2b(vv);
            }
        }
    }
}

__global__ __launch_bounds__(256) void gemm_bias_f32(
    const unsigned short* __restrict__ A,
    const unsigned short* __restrict__ BT,
    const float* __restrict__ bias,
    float* __restrict__ Cout, int N, int K)
{
    __shared__ unsigned short As[128 * 32];
    __shared__ unsigned short Bs[128 * 32];
    gemm_body<1>(A, BT, bias, (void*)Cout, N, K, As, Bs);
}

__global__ __launch_bounds__(256) void gemm3(
    const unsigned short* __restrict__ Abase,
    const unsigned short* __restrict__ WT,
    const float* __restrict__ bq, const float* __restrict__ bk, const float* __restrict__ bv,
    unsigned short* __restrict__ Cbase)
{
    __shared__ unsigned short As[128 * 32];
    __shared__ unsigned short Bs[128 * 32];
    const int z = blockIdx.z;
    const unsigned short* A  = Abase + (long)z * 4194304;
    const unsigned short* BT = WT    + (long)z * 1048576;
    unsigned short*       C  = Cbase + (long)z * 4194304;
    const float* bias = (z == 0) ? bq : (z == 1) ? bk : bv;
    gemm_body<0>(A, BT, bias, (void*)C, 1024, 1024, As, Bs);
}

// ---------------- fused attention ---------------------------------------------
// IBLK=32 i-rows; GROUP=32 j; 16 groups over a 512-j half; grid 256.
// Software-pipelined, 2 __syncthreads per group, NO manual fences:
//   phase 1 (MFMA): QK(g) -> Se/So  +  PV(g-1) reads P
//   phase 2 (VALU): softmax(g) reads Se/So -> writes P; prefetch kf(g+1), vf(g)
// Se, So, P are separate buffers (108KB LDS) -> no alias ordering constraints.
// launch_bounds(512,1): 256-VGPR budget so prefetches stay a group ahead.
__global__ __launch_bounds__(512, 1) void attn_fused(
    const unsigned short* __restrict__ Q,    // [4096][1024]
    const unsigned short* __restrict__ Kg_,  // [4096][1024]
    const unsigned short* __restrict__ Vt,   // [4][1024(d)][1024(s)]
    const int* __restrict__ mask,            // [1024*1024]
    unsigned short* __restrict__ P0,
    unsigned short* __restrict__ P1)
{
    __shared__ __align__(16) unsigned char smem[110592];
    float*         Se = (float*)smem;                 // [512 ij][18 f32] (72B rows)
    float*         So = (float*)(smem + 36864);       // [512 ij][18 f32]
    unsigned char* Pb = smem + 73728;                 // [16 h][32 i][72B]

    const int tid = threadIdx.x, w = tid >> 6, lane = tid & 63;
    const int l15 = lane & 15, l4 = lane >> 4;
    const int h0  = 2 * w;
    const int sxor = h0 ^ (l4 << 2);

    // bijective XCD swizzle: 256 blocks -> 32 consecutive wg per XCD
    const int bid = blockIdx.x;
    const int wg  = (bid & 7) * 32 + (bid >> 3);
    const int b   = wg >> 6;
    const int jh  = (wg >> 5) & 1;
    const int i0  = (wg & 31) << 5;
    const int jbase = jh << 9;

    const unsigned short* Kb = Kg_ + (long)b * 1048576;
    const unsigned short* Vb = Vt  + (long)b * 1048576;
    unsigned short* Pout = (jh == 0) ? P0 : P1;

    const int si = tid >> 4, sj = tid & 15;    // softmax thread -> (i row, j col)
    const int xorv = si & 12;                  // un-permutes the S h-slots
    const int mrow = (i0 + si) * 1024 + jbase;

    // ---- Q fragments (persistent)
    bf16x8 qf[2][2][2];   // [isub][hh][ks]
    #pragma unroll
    for (int is = 0; is < 2; is++)
        #pragma unroll
        for (int hh = 0; hh < 2; hh++)
            #pragma unroll
            for (int ks = 0; ks < 2; ks++)
                qf[is][hh][ks] = *(const bf16x8*)(Q + (long)(b*1024 + i0 + is*16 + l15) * 1024
                                                  + (h0 + hh) * 64 + ks * 32 + l4 * 8);

#define LOAD_KF(J0) do { \
    _Pragma("unroll") \
    for (int t_ = 0; t_ < 2; t_++) \
        _Pragma("unroll") \
        for (int hh = 0; hh < 2; hh++) \
            _Pragma("unroll") \
            for (int ks = 0; ks < 2; ks++) \
                kf[t_][hh][ks] = *(const bf16x8*)(Kb + (long)((J0) + t_*16 + l15) * 1024 \
                                                   + (h0 + hh) * 64 + ks * 32 + l4 * 8); \
    } while(0)

#define LOAD_VF(J0) do { \
    _Pragma("unroll") \
    for (int hh = 0; hh < 2; hh++) \
        _Pragma("unroll") \
        for (int n = 0; n < 4; n++) \
            vf[hh][n] = *(const bf16x8*)(Vb + (long)((h0 + hh) * 64 + n * 16 + l15) * 1024 \
                                           + (J0) + l4 * 8); \
    } while(0)

// QK for group with j0: both 16-j subtiles into Se/So
#define DO_QK() do { \
    _Pragma("unroll") \
    for (int t_ = 0; t_ < 2; t_++) { \
        float* St = t_ ? So : Se; \
        _Pragma("unroll") \
        for (int is = 0; is < 2; is++) { \
            f32x4 sv0 = (f32x4){0.f,0.f,0.f,0.f}, sv1 = (f32x4){0.f,0.f,0.f,0.f}; \
            sv0 = __builtin_amdgcn_mfma_f32_16x16x32_bf16(qf[is][0][0], kf[t_][0][0], sv0, 0, 0, 0); \
            sv0 = __builtin_amdgcn_mfma_f32_16x16x32_bf16(qf[is][0][1], kf[t_][0][1], sv0, 0, 0, 0); \
            sv1 = __builtin_amdgcn_mfma_f32_16x16x32_bf16(qf[is][1][0], kf[t_][1][0], sv1, 0, 0, 0); \
            sv1 = __builtin_amdgcn_mfma_f32_16x16x32_bf16(qf[is][1][1], kf[t_][1][1], sv1, 0, 0, 0); \
            _Pragma("unroll") \
            for (int r = 0; r < 4; r++) { \
                const int ij = (is*16 + l4*4 + r) * 16 + l15; \
                f32x2 pr; pr[0] = sv0[r]; pr[1] = sv1[r]; \
                *(f32x2*)(St + ij * 18 + sxor) = pr; \
            } \
        } \
    } } while(0)

// PV over the previous group's P (full K=32), using vf of that group
#define DO_PV() do { \
    bf16x8 pa[2][2]; \
    _Pragma("unroll") \
    for (int is = 0; is < 2; is++) \
        _Pragma("unroll") \
        for (int hh = 0; hh < 2; hh++) { \
            const unsigned char* pr = Pb + (h0 + hh) * 2304 + (is*16 + l15) * 72 + l4 * 16; \
            bf16x4 lo = *(const bf16x4*)(pr); \
            bf16x4 hi = *(const bf16x4*)(pr + 8); \
            pa[is][hh] = (bf16x8){lo[0],lo[1],lo[2],lo[3], hi[0],hi[1],hi[2],hi[3]}; \
        } \
    _Pragma("unroll") \
    for (int is = 0; is < 2; is++) \
        _Pragma("unroll") \
        for (int hh = 0; hh < 2; hh++) \
            _Pragma("unroll") \
            for (int n = 0; n < 4; n++) \
                acc[is][hh][n] = __builtin_amdgcn_mfma_f32_16x16x32_bf16(pa[is][hh], vf[hh][n], acc[is][hh][n], 0, 0, 0); \
    } while(0)

// softmax both subtiles of group g (mask values mke/mko), write P
#define DO_SOFTMAX(MKE, MKO) do { \
    _Pragma("unroll") \
    for (int t_ = 0; t_ < 2; t_++) { \
        const float* sp = (t_ ? So : Se) + (si * 16 + sj) * 18; \
        const int    mk = t_ ? (MKO) : (MKE); \
        const int    jc = t_ * 16 + sj; \
        float tv[16]; \
        _Pragma("unroll") \
        for (int q_ = 0; q_ < 8; q_++) { \
            const f32x2 t2 = *(const f32x2*)(sp + q_ * 2); \
            tv[q_*2] = t2[0]; tv[q_*2+1] = t2[1]; \
        } \
        float Z = 0.f; \
        _Pragma("unroll") \
        for (int h = 0; h < 16; h++) { \
            float x = tv[h] * 0.18033688f;   /* 0.125 * log2(e) */ \
            if (mk == 0) x = -__builtin_inff(); \
            float e; asm("v_exp_f32 %0, %1" : "=v"(e) : "v"(x)); \
            tv[h] = e; Z += e; \
        } \
        float inv; asm("v_rcp_f32 %0, %1" : "=v"(inv) : "v"(Z)); \
        _Pragma("unroll") \
        for (int h = 0; h < 16; h++) { \
            const unsigned p16 = (__float_as_uint(tv[h] * inv) + 0x8000u) >> 16; \
            *(unsigned short*)(Pb + (h ^ xorv) * 2304 + si * 72 + jc * 2) = (unsigned short)p16; \
        } \
    } } while(0)

    bf16x8 kf[2][2][2];   // [tile e/o][hh][ks]
    bf16x8 vf[2][4];      // [hh][n]  (vf of group g, consumed by PV in phase1 of g+1)

    f32x4 acc[2][2][4];   // [isub][hh][n]
    #pragma unroll
    for (int is = 0; is < 2; is++)
        #pragma unroll
        for (int hh = 0; hh < 2; hh++)
            #pragma unroll
            for (int n = 0; n < 4; n++)
                acc[is][hh][n] = (f32x4){0.f, 0.f, 0.f, 0.f};

    // ---- prologue: group 0 QK + softmax
    LOAD_KF(jbase);
    LOAD_VF(jbase);
    DO_QK();
    __syncthreads();
    {
        const int mke = mask[mrow + sj];
        const int mko = mask[mrow + 16 + sj];
        DO_SOFTMAX(mke, mko);
    }
    LOAD_KF(jbase + 32);
    __syncthreads();

    for (int g = 1; g < 16; ++g) {
        const int j0 = jbase + g * 32;
        // phase 1: MFMA — QK(g) into Se/So, PV(g-1) from P + vf(g-1)
        DO_QK();
        DO_PV();
        __syncthreads();
        // phase 2: VALU — softmax(g) -> P; prefetch kf(g+1), vf(g)
        {
            const int mke = mask[mrow + g * 32 + sj];
            const int mko = mask[mrow + g * 32 + 16 + sj];
            DO_SOFTMAX(mke, mko);
        }
        if (g < 15) LOAD_KF(j0 + 32);
        LOAD_VF(j0);
        __syncthreads();
    }
    // epilogue: PV(15)
    DO_PV();

    // ---- epilogue: bf16 partial
    #pragma unroll
    for (int is = 0; is < 2; is++)
        #pragma unroll
        for (int hh = 0; hh < 2; hh++)
            #pragma unroll
            for (int n = 0; n < 4; n++)
                #pragma unroll
                for (int r = 0; r < 4; r++) {
                    const long row = b * 1024 + i0 + is * 16 + l4 * 4 + r;
                    Pout[row * 1024 + (h0 + hh) * 64 + n * 16 + l15] = f2b(acc[is][hh][n][r]);
                }
#undef LOAD_KF
#undef LOAD_VF
#undef DO_QK
#undef DO_PV
#undef DO_SOFTMAX
}

// ---------------- reduce: P0 += P1 (bf16, in place) ---------------------------
__global__ __launch_bounds__(256) void addp(
    unsigned short* __restrict__ P0, const unsigned short* __restrict__ P1)
{
    const long i = ((long)blockIdx.x * 256 + threadIdx.x) * 8;
    ushort4 a0 = *(const ushort4*)(P0 + i);
    ushort4 a1 = *(const ushort4*)(P0 + i + 4);
    ushort4 b0 = *(const ushort4*)(P1 + i);
    ushort4 b1 = *(const ushort4*)(P1 + i + 4);
    ushort4 o0, o1;
    o0.x = f2b(b2f(a0.x) + b2f(b0.x)); o0.y = f2b(b2f(a0.y) + b2f(b0.y));
    o0.z = f2b(b2f(a0.z) + b2f(b0.z)); o0.w = f2b(b2f(a0.w) + b2f(b0.w));
    o1.x = f2b(b2f(a1.x) + b2f(b1.x)); o1.y = f2b(b2f(a1.y) + b2f(b1.y));
    o1.z = f2b(b2f(a1.z) + b2f(b1.z)); o1.w = f2b(b2f(a1.w) + b2f(b1.w));
    *(ushort4*)(P0 + i) = o0;
    *(ushort4*)(P0 + i + 4) = o1;
}

extern "C" void kernel_launch(void* const* d_in, const int* in_sizes, int n_in,
                              void* d_out, int out_size, void* d_ws, size_t ws_size,
                              hipStream_t stream)
{
    const float* q    = (const float*)d_in[0];
    const float* k    = (const float*)d_in[1];
    const float* v    = (const float*)d_in[2];
    const int*   mask = (const int*)  d_in[3];
    const float* Wq   = (const float*)d_in[4];
    const float* bq   = (const float*)d_in[5];
    const float* Wk   = (const float*)d_in[6];
    const float* bk   = (const float*)d_in[7];
    const float* Wv   = (const float*)d_in[8];
    const float* bv   = (const float*)d_in[9];
    const float* Wo   = (const float*)d_in[10];
    const float* bo   = (const float*)d_in[11];

    unsigned short* ws = (unsigned short*)d_ws;
    const long MS = 1048576;
    unsigned short* WT  = ws;             // 4 transposed weights      [0,4M)
    unsigned short* Xq  = ws + 4*MS;      // bf16 query  -> later Vt   [4M,8M)
    unsigned short* Xk  = ws + 8*MS;      // bf16 key    -> later P0   [8M,12M)
    unsigned short* Xv  = ws + 12*MS;     // bf16 value                [12M,16M)
    unsigned short* Qm  = ws + 16*MS;     // Q projection              [16M,20M)
    unsigned short* Km  = ws + 20*MS;     // K projection              [20M,24M)
    unsigned short* Vm  = ws + 24*MS;     // V projection -> later P1  [24M,28M)
    unsigned short* Vtm = Xq;
    unsigned short* P0  = Xk;
    unsigned short* P1  = Vm;

    convert_qkv<<<12288, 256, 0, stream>>>(q, k, v, Xq);
    wtrans<<<dim3(32, 32, 4), dim3(32, 8), 0, stream>>>(Wq, Wk, Wv, Wo, WT);
    gemm3<<<dim3(32, 8, 3), 256, 0, stream>>>(Xq, WT, bq, bk, bv, Qm);
    vtrans<<<dim3(32, 32, 4), dim3(32, 8), 0, stream>>>(Vm, Vtm);
    attn_fused<<<256, 512, 0, stream>>>(Qm, Km, Vtm, mask, P0, P1);
    addp<<<2048, 256, 0, stream>>>(P0, P1);
    gemm_bias_f32<<<dim3(32, 8), 256, 0, stream>>>(P0, WT + 3*MS, bo, (float*)d_out, 1024, 1024);
}

// Round 13
// 157.438 us; speedup vs baseline: 1.4188x; 1.1970x over previous
//
#include <hip/hip_runtime.h>
#include <hip/hip_bf16.h>

// B=4, S=1024, D=1024, H=16, DH=64. Softmax over HEADS (per (i,j)), per reference.

using f32x4  = __attribute__((ext_vector_type(4))) float;
using f32x2  = __attribute__((ext_vector_type(2))) float;
using bf16x8 = __attribute__((ext_vector_type(8))) short;
using bf16x4 = __attribute__((ext_vector_type(4))) short;

__device__ inline unsigned short f2b(float f){
    unsigned u = __float_as_uint(f);
    unsigned r = (u + 0x7fffu + ((u >> 16) & 1u)) >> 16;
    return (unsigned short)r;
}
__device__ inline float b2f(unsigned short s){
    return __uint_as_float(((unsigned)s) << 16);
}

#define GLL16(gp, lp) __builtin_amdgcn_global_load_lds( \
    (const __attribute__((address_space(1))) void*)(gp), \
    (__attribute__((address_space(3))) void*)(lp), 16, 0, 0)

#define LGKM0 do { asm volatile("s_waitcnt lgkmcnt(0)" ::: "memory"); \
                   __builtin_amdgcn_sched_barrier(0); } while(0)
#define BAR   do { __builtin_amdgcn_s_barrier(); \
                   __builtin_amdgcn_sched_barrier(0); } while(0)

// ---------------- convert q,k,v f32 -> bf16, contiguous [3][4096][1024] -------
__global__ __launch_bounds__(256) void convert_qkv(
    const float* __restrict__ q, const float* __restrict__ k, const float* __restrict__ v,
    unsigned short* __restrict__ dst)
{
    const long gid = (long)blockIdx.x * 256 + threadIdx.x;
    const int  t   = (int)(gid >> 20);
    const long off = (gid & 1048575) << 2;
    const float* src = (t == 0) ? q : (t == 1) ? k : v;
    const float4 x = *(const float4*)(src + off);
    ushort4 o;
    o.x = f2b(x.x); o.y = f2b(x.y); o.z = f2b(x.z); o.w = f2b(x.w);
    *(ushort4*)(dst + (long)t * 4194304 + off) = o;
}

// ---------------- transpose+convert W f32 [k][n] -> bf16 [n][k] ---------------
__global__ __launch_bounds__(256) void wtrans(
    const float* __restrict__ w0, const float* __restrict__ w1,
    const float* __restrict__ w2, const float* __restrict__ w3,
    unsigned short* __restrict__ out)
{
    const float* W = (blockIdx.z == 0) ? w0 : (blockIdx.z == 1) ? w1 : (blockIdx.z == 2) ? w2 : w3;
    unsigned short* O = out + (long)blockIdx.z * 1048576;
    __shared__ float t[32][33];
    const int n0 = blockIdx.x * 32, k0 = blockIdx.y * 32;
    const int tx = threadIdx.x, ty = threadIdx.y;
    #pragma unroll
    for (int i = 0; i < 4; i++)
        t[ty + 8*i][tx] = W[(long)(k0 + ty + 8*i) * 1024 + n0 + tx];
    __syncthreads();
    #pragma unroll
    for (int i = 0; i < 4; i++)
        O[(long)(n0 + ty + 8*i) * 1024 + k0 + tx] = f2b(t[tx][ty + 8*i]);
}

// ---------------- K -> MFMA fragment layout -----------------------------------
// Kf[b][jt(64)][hk(32=h*2+ks)][lane(64)][e(8)]:
//   Kf(...) = Km[b][jt*16 + (l&15)][ (hk>>1)*64 + (hk&1)*32 + (l>>4)*8 + e ]
__global__ __launch_bounds__(256) void kf_trans(
    const unsigned short* __restrict__ Km, unsigned short* __restrict__ Kf)
{
    const int b = blockIdx.y, jt = blockIdx.x;
    __shared__ unsigned short t[16][1032];
    const int tid = threadIdx.x;
    #pragma unroll
    for (int p = 0; p < 8; p++) {
        const int idx = p * 2048 + tid * 8;
        const int r = idx >> 10, c = idx & 1023;
        *(uint4*)&t[r][c] = *(const uint4*)(Km + (long)(b*1024 + jt*16 + r) * 1024 + c);
    }
    __syncthreads();
    #pragma unroll
    for (int p = 0; p < 8; p++) {
        const int o  = p * 2048 + tid * 8;
        const int hk = o >> 9;
        const int l  = (o >> 3) & 63;
        const int cc = (hk >> 1) * 64 + (hk & 1) * 32 + (l >> 4) * 8;
        *(uint4*)(Kf + (long)(b*64 + jt) * 16384 + o) = *(const uint4*)&t[l & 15][cc];
    }
}

// ---------------- V -> MFMA fragment layout -----------------------------------
// Vf[b][jg(32)][hn(64=h*4+n)][lane(64)][e(8)]:
//   Vf(...) = Vm[b][jg*32 + (l>>4)*8 + e][ (hn>>2)*64 + (hn&3)*16 + (l&15) ]
__global__ __launch_bounds__(256) void vf_trans(
    const unsigned short* __restrict__ Vm, unsigned short* __restrict__ Vf)
{
    const int b = blockIdx.y, jg = blockIdx.x;
    __shared__ unsigned short t[32][1032];
    const int tid = threadIdx.x;
    #pragma unroll
    for (int p = 0; p < 16; p++) {
        const int idx = p * 2048 + tid * 8;
        const int r = idx >> 10, c = idx & 1023;
        *(uint4*)&t[r][c] = *(const uint4*)(Vm + (long)(b*1024 + jg*32 + r) * 1024 + c);
    }
    __syncthreads();
    #pragma unroll
    for (int p = 0; p < 16; p++) {
        const int o  = p * 2048 + tid * 8;
        const int hn = o >> 9;
        const int l  = (o >> 3) & 63;
        const int col = (hn >> 2) * 64 + (hn & 3) * 16 + (l & 15);
        const int r0  = (l >> 4) * 8;
        unsigned short vv[8];
        #pragma unroll
        for (int e = 0; e < 8; e++) vv[e] = t[r0 + e][col];
        *(uint4*)(Vf + (long)(b*32 + jg) * 32768 + o) = *(const uint4*)vv;
    }
}

// ---------------- GEMM tile body (m97 structure) ------------------------------
template<int OUTF32>
__device__ __forceinline__ void gemm_body(
    const unsigned short* __restrict__ A,
    const unsigned short* __restrict__ BT,
    const float* __restrict__ bias,
    void* __restrict__ Cout, int N, int K,
    unsigned short* As, unsigned short* Bs)
{
    const int tid  = threadIdx.x;
    const int wave = tid >> 6, lane = tid & 63;
    const int l15  = lane & 15, l4 = lane >> 4;
    const int wr   = wave >> 1, wc = wave & 1;
    const long rowBase = (long)blockIdx.x * 128;
    const long colBase = (long)blockIdx.y * 128;

    f32x4 acc[4][4];
    #pragma unroll
    for (int m = 0; m < 4; m++)
        #pragma unroll
        for (int n = 0; n < 4; n++)
            acc[m][n] = (f32x4){0.f, 0.f, 0.f, 0.f};

    const int c0    = wave * 2;
    const int srow0 = c0 * 16 + (lane >> 2);
    const int srow1 = srow0 + 16;
    const int skk   = (lane & 3) * 8;

    for (int k0 = 0; k0 < K; k0 += 32) {
        GLL16(A  + (rowBase + srow0) * K + k0 + skk, As + c0 * 512);
        GLL16(A  + (rowBase + srow1) * K + k0 + skk, As + (c0 + 1) * 512);
        GLL16(BT + (colBase + srow0) * K + k0 + skk, Bs + c0 * 512);
        GLL16(BT + (colBase + srow1) * K + k0 + skk, Bs + (c0 + 1) * 512);
        __syncthreads();
        bf16x8 af[4], bfr[4];
        #pragma unroll
        for (int m = 0; m < 4; m++)
            af[m] = *(const bf16x8*)(As + (wr*64 + m*16 + l15) * 32 + l4 * 8);
        #pragma unroll
        for (int n = 0; n < 4; n++)
            bfr[n] = *(const bf16x8*)(Bs + (wc*64 + n*16 + l15) * 32 + l4 * 8);
        #pragma unroll
        for (int m = 0; m < 4; m++)
            #pragma unroll
            for (int n = 0; n < 4; n++)
                acc[m][n] = __builtin_amdgcn_mfma_f32_16x16x32_bf16(af[m], bfr[n], acc[m][n], 0, 0, 0);
        __syncthreads();
    }

    #pragma unroll
    for (int m = 0; m < 4; m++) {
        const long row = rowBase + wr*64 + m*16 + l4*4;
        #pragma unroll
        for (int n = 0; n < 4; n++) {
            const long col = colBase + wc*64 + n*16 + l15;
            const float bv = bias[col];
            #pragma unroll
            for (int r = 0; r < 4; r++) {
                const float vv = acc[m][n][r] + bv;
                if (OUTF32) ((float*)Cout)[(row + r) * N + col] = vv;
                else        ((unsigned short*)Cout)[(row + r) * N + col] = f2b(vv);
            }
        }
    }
}

__global__ __launch_bounds__(256) void gemm_bias_f32(
    const unsigned short* __restrict__ A,
    const unsigned short* __restrict__ BT,
    const float* __restrict__ bias,
    float* __restrict__ Cout, int N, int K)
{
    __shared__ unsigned short As[128 * 32];
    __shared__ unsigned short Bs[128 * 32];
    gemm_body<1>(A, BT, bias, (void*)Cout, N, K, As, Bs);
}

__global__ __launch_bounds__(256) void gemm3(
    const unsigned short* __restrict__ Abase,
    const unsigned short* __restrict__ WT,
    const float* __restrict__ bq, const float* __restrict__ bk, const float* __restrict__ bv,
    unsigned short* __restrict__ Cbase)
{
    __shared__ unsigned short As[128 * 32];
    __shared__ unsigned short Bs[128 * 32];
    const int z = blockIdx.z;
    const unsigned short* A  = Abase + (long)z * 4194304;
    const unsigned short* BT = WT    + (long)z * 1048576;
    unsigned short*       C  = Cbase + (long)z * 4194304;
    const float* bias = (z == 0) ? bq : (z == 1) ? bk : bv;
    gemm_body<0>(A, BT, bias, (void*)C, 1024, 1024, As, Bs);
}

// ---------------- fused attention ---------------------------------------------
// Round-9 structure (raw barriers, 4 phases, S/P alias, 72KB LDS, 128-VGPR cap)
// with K/V loads from PRE-PACKED fragment layouts Kf/Vf: every load is
// base + lane*16 -> one coalesced 1KB wave-load (was 16-line scatter).
__global__ __launch_bounds__(512, 2) void attn_fused(
    const unsigned short* __restrict__ Q,    // [4096][1024]
    const unsigned short* __restrict__ Kf_,  // packed [4][64][32][64][8]
    const unsigned short* __restrict__ Vf_,  // packed [4][32][64][64][8]
    const int* __restrict__ mask,            // [1024*1024]
    unsigned short* __restrict__ P0,
    unsigned short* __restrict__ P1)
{
    __shared__ __align__(16) unsigned char smem[73728];
    float*         Se = (float*)smem;                 // [512 ij][18 f32] (72B rows)
    float*         So = (float*)(smem + 36864);       // [512 ij][18 f32]
    unsigned char* Pb = smem;                         // [16 h][32 i][72B], aliases Se

    const int tid = threadIdx.x, w = tid >> 6, lane = tid & 63;
    const int l15 = lane & 15, l4 = lane >> 4;
    const int h0  = 2 * w;
    const int sxor = h0 ^ (l4 << 2);

    // bijective XCD swizzle: 256 blocks -> 32 consecutive wg per XCD
    const int bid = blockIdx.x;
    const int wg  = (bid & 7) * 32 + (bid >> 3);
    const int b   = wg >> 6;
    const int jh  = (wg >> 5) & 1;
    const int i0  = (wg & 31) << 5;
    const int jbase = jh << 9;

    const unsigned short* Kfb = Kf_ + (long)b * 1048576;
    const unsigned short* Vfb = Vf_ + (long)b * 1048576;
    unsigned short* Pout = (jh == 0) ? P0 : P1;

    const int si = tid >> 4, sj = tid & 15;    // softmax thread -> (i row, j col)
    const int xorv = si & 12;                  // un-permutes the S h-slots
    const int mrow = (i0 + si) * 1024 + jbase;

    // ---- Q fragments (persistent; one-time scattered load)
    bf16x8 qf[2][2][2];   // [isub][hh][ks]
    #pragma unroll
    for (int is = 0; is < 2; is++)
        #pragma unroll
        for (int hh = 0; hh < 2; hh++)
            #pragma unroll
            for (int ks = 0; ks < 2; ks++)
                qf[is][hh][ks] = *(const bf16x8*)(Q + (long)(b*1024 + i0 + is*16 + l15) * 1024
                                                  + (h0 + hh) * 64 + ks * 32 + l4 * 8);

#define LOAD_KF(JT) do { \
    _Pragma("unroll") \
    for (int t_ = 0; t_ < 2; t_++) \
        _Pragma("unroll") \
        for (int hh = 0; hh < 2; hh++) \
            _Pragma("unroll") \
            for (int ks = 0; ks < 2; ks++) \
                kf[t_][hh][ks] = *(const bf16x8*)(Kfb + ((JT) + t_) * 16384 \
                                                   + ((h0 + hh) * 2 + ks) * 512 + lane * 8); \
    } while(0)

#define LOAD_VF(JG) do { \
    _Pragma("unroll") \
    for (int hh = 0; hh < 2; hh++) \
        _Pragma("unroll") \
        for (int n = 0; n < 4; n++) \
            vf[hh][n] = *(const bf16x8*)(Vfb + (long)(JG) * 32768 \
                                           + ((h0 + hh) * 4 + n) * 512 + lane * 8); \
    } while(0)

    bf16x8 kf[2][2][2];   // [tile e/o][hh][ks]
    bf16x8 vf[2][4];      // [hh][n]
    LOAD_KF(jh*32);
    LOAD_VF(jh*16);

    f32x4 acc[2][2][4];   // [isub][hh][n]
    #pragma unroll
    for (int is = 0; is < 2; is++)
        #pragma unroll
        for (int hh = 0; hh < 2; hh++)
            #pragma unroll
            for (int n = 0; n < 4; n++)
                acc[is][hh][n] = (f32x4){0.f, 0.f, 0.f, 0.f};

    for (int g = 0; g < 16; ++g) {
        const int mke = mask[mrow + g * 32 + sj];
        const int mko = mask[mrow + g * 32 + 16 + sj];

        // ---- QK^T for both tiles (kf in regs)
        #pragma unroll
        for (int t_ = 0; t_ < 2; t_++) {
            float* St = t_ ? So : Se;
            #pragma unroll
            for (int is = 0; is < 2; is++) {
                f32x4 sv0 = (f32x4){0.f,0.f,0.f,0.f}, sv1 = (f32x4){0.f,0.f,0.f,0.f};
                sv0 = __builtin_amdgcn_mfma_f32_16x16x32_bf16(qf[is][0][0], kf[t_][0][0], sv0, 0, 0, 0);
                sv0 = __builtin_amdgcn_mfma_f32_16x16x32_bf16(qf[is][0][1], kf[t_][0][1], sv0, 0, 0, 0);
                sv1 = __builtin_amdgcn_mfma_f32_16x16x32_bf16(qf[is][1][0], kf[t_][1][0], sv1, 0, 0, 0);
                sv1 = __builtin_amdgcn_mfma_f32_16x16x32_bf16(qf[is][1][1], kf[t_][1][1], sv1, 0, 0, 0);
                #pragma unroll
                for (int r = 0; r < 4; r++) {
                    const int ij = (is*16 + l4*4 + r) * 16 + l15;
                    f32x2 pr; pr[0] = sv0[r]; pr[1] = sv1[r];
                    *(f32x2*)(St + ij * 18 + sxor) = pr;
                }
            }
        }
        LGKM0; BAR;                      // B1: S_e, S_o visible

        if (g < 15) LOAD_KF(jh*32 + (g + 1) * 2);   // coalesced refill for g+1

        // ---- softmax tile e (reads Se); packed result held across B2
        unsigned pe[8];
        {
            const float* sp = Se + tid * 18;
            float tv[16];
            #pragma unroll
            for (int q_ = 0; q_ < 8; q_++) {
                const f32x2 t2 = *(const f32x2*)(sp + q_ * 2);
                tv[q_*2] = t2[0]; tv[q_*2+1] = t2[1];
            }
            float Z = 0.f;
            #pragma unroll
            for (int h = 0; h < 16; h++) {
                float x = tv[h] * 0.18033688f;   // 0.125 * log2(e)
                if (mke == 0) x = -__builtin_inff();
                float e; asm("v_exp_f32 %0, %1" : "=v"(e) : "v"(x));
                tv[h] = e; Z += e;
            }
            float inv; asm("v_rcp_f32 %0, %1" : "=v"(inv) : "v"(Z));
            #pragma unroll
            for (int h = 0; h < 8; h++) {
                const unsigned lo = (__float_as_uint(tv[2*h]   * inv) + 0x8000u) >> 16;
                const unsigned hi = (__float_as_uint(tv[2*h+1] * inv) + 0x8000u) >> 16;
                pe[h] = lo | (hi << 16);
            }
        }
        BAR;                             // B2: ALL Se reads done -> P may overwrite
        #pragma unroll
        for (int h = 0; h < 16; h++) {
            const unsigned short pv = (unsigned short)((h & 1) ? (pe[h >> 1] >> 16) : pe[h >> 1]);
            *(unsigned short*)(Pb + (h ^ xorv) * 2304 + si * 72 + sj * 2) = pv;
        }

        // ---- softmax tile o (reads So: NOT aliased, safe during P writes)
        {
            const float* sp = So + tid * 18;
            float tv[16];
            #pragma unroll
            for (int q_ = 0; q_ < 8; q_++) {
                const f32x2 t2 = *(const f32x2*)(sp + q_ * 2);
                tv[q_*2] = t2[0]; tv[q_*2+1] = t2[1];
            }
            float Z = 0.f;
            #pragma unroll
            for (int h = 0; h < 16; h++) {
                float x = tv[h] * 0.18033688f;
                if (mko == 0) x = -__builtin_inff();
                float e; asm("v_exp_f32 %0, %1" : "=v"(e) : "v"(x));
                tv[h] = e; Z += e;
            }
            float inv; asm("v_rcp_f32 %0, %1" : "=v"(inv) : "v"(Z));
            #pragma unroll
            for (int h = 0; h < 16; h++) {
                const unsigned p16 = (__float_as_uint(tv[h] * inv) + 0x8000u) >> 16;
                *(unsigned short*)(Pb + (h ^ xorv) * 2304 + si * 72 + 32 + sj * 2) = (unsigned short)p16;
            }
        }
        LGKM0; BAR;                      // B3: P visible

        // ---- PV, full K=32 (P rows 72B -> paired b64 reads)
        {
            bf16x8 pa[2][2];
            #pragma unroll
            for (int is = 0; is < 2; is++)
                #pragma unroll
                for (int hh = 0; hh < 2; hh++) {
                    const unsigned char* pr = Pb + (h0 + hh) * 2304 + (is*16 + l15) * 72 + l4 * 16;
                    bf16x4 lo = *(const bf16x4*)(pr);
                    bf16x4 hi = *(const bf16x4*)(pr + 8);
                    pa[is][hh] = (bf16x8){lo[0],lo[1],lo[2],lo[3], hi[0],hi[1],hi[2],hi[3]};
                }
            #pragma unroll
            for (int is = 0; is < 2; is++)
                #pragma unroll
                for (int hh = 0; hh < 2; hh++)
                    #pragma unroll
                    for (int n = 0; n < 4; n++)
                        acc[is][hh][n] = __builtin_amdgcn_mfma_f32_16x16x32_bf16(pa[is][hh], vf[hh][n], acc[is][hh][n], 0, 0, 0);
        }
        if (g < 15) {
            LOAD_VF(jh*16 + g + 1);      // coalesced refill for g+1
            BAR;                         // B4: P reads done; next QK may write Se
        }
    }

    // ---- epilogue: bf16 partial
    #pragma unroll
    for (int is = 0; is < 2; is++)
        #pragma unroll
        for (int hh = 0; hh < 2; hh++)
            #pragma unroll
            for (int n = 0; n < 4; n++)
                #pragma unroll
                for (int r = 0; r < 4; r++) {
                    const long row = b * 1024 + i0 + is * 16 + l4 * 4 + r;
                    Pout[row * 1024 + (h0 + hh) * 64 + n * 16 + l15] = f2b(acc[is][hh][n][r]);
                }
#undef LOAD_KF
#undef LOAD_VF
}

// ---------------- reduce: P0 += P1 (bf16, in place) ---------------------------
__global__ __launch_bounds__(256) void addp(
    unsigned short* __restrict__ P0, const unsigned short* __restrict__ P1)
{
    const long i = ((long)blockIdx.x * 256 + threadIdx.x) * 8;
    ushort4 a0 = *(const ushort4*)(P0 + i);
    ushort4 a1 = *(const ushort4*)(P0 + i + 4);
    ushort4 b0 = *(const ushort4*)(P1 + i);
    ushort4 b1 = *(const ushort4*)(P1 + i + 4);
    ushort4 o0, o1;
    o0.x = f2b(b2f(a0.x) + b2f(b0.x)); o0.y = f2b(b2f(a0.y) + b2f(b0.y));
    o0.z = f2b(b2f(a0.z) + b2f(b0.z)); o0.w = f2b(b2f(a0.w) + b2f(b0.w));
    o1.x = f2b(b2f(a1.x) + b2f(b1.x)); o1.y = f2b(b2f(a1.y) + b2f(b1.y));
    o1.z = f2b(b2f(a1.z) + b2f(b1.z)); o1.w = f2b(b2f(a1.w) + b2f(b1.w));
    *(ushort4*)(P0 + i) = o0;
    *(ushort4*)(P0 + i + 4) = o1;
}

extern "C" void kernel_launch(void* const* d_in, const int* in_sizes, int n_in,
                              void* d_out, int out_size, void* d_ws, size_t ws_size,
                              hipStream_t stream)
{
    const float* q    = (const float*)d_in[0];
    const float* k    = (const float*)d_in[1];
    const float* v    = (const float*)d_in[2];
    const int*   mask = (const int*)  d_in[3];
    const float* Wq   = (const float*)d_in[4];
    const float* bq   = (const float*)d_in[5];
    const float* Wk   = (const float*)d_in[6];
    const float* bk   = (const float*)d_in[7];
    const float* Wv   = (const float*)d_in[8];
    const float* bv   = (const float*)d_in[9];
    const float* Wo   = (const float*)d_in[10];
    const float* bo   = (const float*)d_in[11];

    unsigned short* ws = (unsigned short*)d_ws;
    const long MS = 1048576;
    unsigned short* WT  = ws;             // 4 transposed weights      [0,4M)
    unsigned short* Xq  = ws + 4*MS;      // bf16 query  -> later Kf   [4M,8M)
    unsigned short* Xk  = ws + 8*MS;      // bf16 key    -> later P0   [8M,12M)
    unsigned short* Xv  = ws + 12*MS;     // bf16 value  -> later Vf   [12M,16M)
    unsigned short* Qm  = ws + 16*MS;     // Q projection              [16M,20M)
    unsigned short* Km  = ws + 20*MS;     // K projection              [20M,24M)
    unsigned short* Vm  = ws + 24*MS;     // V projection -> later P1  [24M,28M)
    unsigned short* Kf  = Xq;             // packed K (Xq dead after gemm3)
    unsigned short* Vf  = Xv;             // packed V (Xv dead after gemm3)
    unsigned short* P0  = Xk;             // attn partial jh=0
    unsigned short* P1  = Vm;             // attn partial jh=1 (Vm dead after vf_trans)

    convert_qkv<<<12288, 256, 0, stream>>>(q, k, v, Xq);
    wtrans<<<dim3(32, 32, 4), dim3(32, 8), 0, stream>>>(Wq, Wk, Wv, Wo, WT);
    gemm3<<<dim3(32, 8, 3), 256, 0, stream>>>(Xq, WT, bq, bk, bv, Qm);
    kf_trans<<<dim3(64, 4), 256, 0, stream>>>(Km, Kf);
    vf_trans<<<dim3(32, 4), 256, 0, stream>>>(Vm, Vf);
    attn_fused<<<256, 512, 0, stream>>>(Qm, Kf, Vf, mask, P0, P1);
    addp<<<2048, 256, 0, stream>>>(P0, P1);
    gemm_bias_f32<<<dim3(32, 8), 256, 0, stream>>>(P0, WT + 3*MS, bo, (float*)d_out, 1024, 1024);
}